// Round 3
// baseline (728.961 us; speedup 1.0000x reference)
//
#include <hip/hip_runtime.h>

#define B_ 64
#define S_ 512
#define D_ 256
#define T_ 4096
#define TS 32
#define NEG 0.01f
#define EPS 1e-5f

// flat d_out layout (all float32):
//   [0, B*T*D)                     out
//   [B*T*D, +B*S)                  log_dur
//   [.., +B)                       mel_len
//   [.., +B*T)                     mel_mask
#define OUT_LOGDUR  (B_*T_*D_)           // 67,108,864
#define OUT_MELLEN  (OUT_LOGDUR + B_*S_) // +32768
#define OUT_MELMASK (OUT_MELLEN + B_)    // +64

// ---------------------------------------------------------------------------
// conv1d(k=3,'SAME') + bias + leaky_relu + layer_norm  (fused, one s-tile/blk)
// LAST=1 additionally computes log_dur = h @ wl + bl (h2 never materialized)
// ---------------------------------------------------------------------------
template<int LAST>
__global__ __launch_bounds__(256)
void conv_ln_kernel(const float* __restrict__ in, const float* __restrict__ w,
                    const float* __restrict__ bias, const float* __restrict__ g,
                    const float* __restrict__ be, const float* __restrict__ wl,
                    const float* __restrict__ bl,
                    const unsigned char* __restrict__ smask,
                    float* __restrict__ hout, float* __restrict__ logdur)
{
    // x staged transposed: xs[channel][s-offset], row stride 36 floats (144B,
    // 16B-aligned for ds_read_b128). Compute reads are wave-uniform -> broadcast.
    __shared__ float xs[D_][TS + 4];
    __shared__ float red[TS][4][2];   // per-wave partial sum / sumsq
    __shared__ float red2[TS][4];     // per-wave partial for log_dur dot

    const int blk = blockIdx.x;
    const int b  = blk / (S_ / TS);
    const int s0 = (blk % (S_ / TS)) * TS;
    const int tid = threadIdx.x;

    // stage rows s0-1 .. s0+TS (34 rows x 256 ch), zero-padded at edges.
    // lane-varying r: LDS write bank = (36*c4 + r) & 31 with c4 uniform per
    // 32-lane group -> each group covers all 32 banks once => conflict-free.
    #pragma unroll
    for (int it = 0; it < 8; ++it) {
        int j  = it * 256 + tid;
        int r  = j & 31;          // row 0..31 (varies per lane)
        int c4 = j >> 5;          // float4 channel group 0..63
        int s  = s0 - 1 + r;
        float4 v = make_float4(0.f, 0.f, 0.f, 0.f);
        if (s >= 0 && s < S_)
            v = ((const float4*)in)[(((b * S_ + s) * D_) >> 2) + c4];
        int c = c4 * 4;
        xs[c][r] = v.x; xs[c+1][r] = v.y; xs[c+2][r] = v.z; xs[c+3][r] = v.w;
    }
    if (tid < 128) {              // remainder rows 32,33
        int r  = 32 + (tid >> 6);
        int c4 = tid & 63;
        int s  = s0 - 1 + r;
        float4 v = make_float4(0.f, 0.f, 0.f, 0.f);
        if (s < S_)
            v = ((const float4*)in)[(((b * S_ + s) * D_) >> 2) + c4];
        int c = c4 * 4;
        xs[c][r] = v.x; xs[c+1][r] = v.y; xs[c+2][r] = v.z; xs[c+3][r] = v.w;
    }
    __syncthreads();

    const int d = tid;
    float acc[TS];
    {
        float bd = bias[d];
        #pragma unroll
        for (int t = 0; t < TS; ++t) acc[t] = bd;
    }

    for (int ci = 0; ci < D_; ++ci) {
        float4 xv4[9];  // 36 floats; indices 0..33 used (uniform b128 broadcasts)
        const float4* xrow = (const float4*)(&xs[ci][0]);
        #pragma unroll
        for (int i = 0; i < 9; ++i) xv4[i] = xrow[i];
        const float* xv = (const float*)xv4;
        #pragma unroll
        for (int k = 0; k < 3; ++k) {
            float wv = w[(k * D_ + ci) * D_ + d];   // coalesced over lanes
            #pragma unroll
            for (int t = 0; t < TS; ++t) acc[t] += xv[t + k] * wv;
        }
    }

    // leaky relu
    #pragma unroll
    for (int t = 0; t < TS; ++t) { float v = acc[t]; acc[t] = v > 0.f ? v : NEG * v; }

    // layer-norm reductions: intra-wave shuffle, inter-wave via LDS
    const int wave = tid >> 6, lane = tid & 63;
    #pragma unroll
    for (int t = 0; t < TS; ++t) {
        float s1 = acc[t], s2 = acc[t] * acc[t];
        #pragma unroll
        for (int o = 32; o > 0; o >>= 1) { s1 += __shfl_xor(s1, o); s2 += __shfl_xor(s2, o); }
        if (lane == 0) { red[t][wave][0] = s1; red[t][wave][1] = s2; }
    }
    __syncthreads();

    const float gd = g[d], bed = be[d];
    const float wld = LAST ? wl[d] : 0.f;
    #pragma unroll
    for (int t = 0; t < TS; ++t) {
        float mu = (red[t][0][0] + red[t][1][0] + red[t][2][0] + red[t][3][0]) * (1.f / D_);
        float m2 = (red[t][0][1] + red[t][1][1] + red[t][2][1] + red[t][3][1]) * (1.f / D_);
        float var = m2 - mu * mu;
        float inv = rsqrtf(var + EPS);
        float h = (acc[t] - mu) * inv * gd + bed;
        if (!LAST) {
            hout[(b * S_ + s0 + t) * D_ + d] = h;
        } else {
            float p = h * wld;
            #pragma unroll
            for (int o = 32; o > 0; o >>= 1) p += __shfl_xor(p, o);
            if (lane == 0) red2[t][wave] = p;
        }
    }
    if (LAST) {
        __syncthreads();
        if (tid < TS) {
            float v = red2[tid][0] + red2[tid][1] + red2[tid][2] + red2[tid][3] + bl[0];
            int i = b * S_ + s0 + tid;
            if (smask[i]) v = 0.f;
            logdur[i] = v;
        }
    }
}

// ---------------------------------------------------------------------------
// per-batch inclusive cumsum of durations; mel_len out as float
// ---------------------------------------------------------------------------
__global__ __launch_bounds__(512)
void scan_kernel(const int* __restrict__ dt, int* __restrict__ cum,
                 float* __restrict__ mellen)
{
    __shared__ int sc[S_];
    const int b = blockIdx.x, tid = threadIdx.x;
    // dur = clip(round(dt + 4.0), 0); dt in [0,5) int -> dt + 4
    int v = dt[b * S_ + tid] + 4;
    sc[tid] = v;
    __syncthreads();
    for (int off = 1; off < S_; off <<= 1) {
        int add = (tid >= off) ? sc[tid - off] : 0;
        __syncthreads();
        sc[tid] += add;
        __syncthreads();
    }
    cum[b * S_ + tid] = sc[tid];
    if (tid == S_ - 1) mellen[b] = (float)sc[tid];
}

// ---------------------------------------------------------------------------
// length-regulator gather: out[b,t,:] = x[b, searchsorted(cum,t,'right'),:] * valid
// + mel_mask passthrough (as float)
// ---------------------------------------------------------------------------
#define RT 16
__global__ __launch_bounds__(256)
void gather_kernel(const float* __restrict__ x, const int* __restrict__ cum,
                   const unsigned char* __restrict__ mm, float* __restrict__ out)
{
    __shared__ int c[S_];
    const int blk = blockIdx.x;
    const int b  = blk / (T_ / RT);
    const int t0 = (blk % (T_ / RT)) * RT;
    const int tid = threadIdx.x;
    c[tid]       = cum[b * S_ + tid];
    c[tid + 256] = cum[b * S_ + tid + 256];
    __syncthreads();
    const int mel = c[S_ - 1];
    const int lane = tid & 63;
    const int sub  = tid >> 6;   // 4 rows in flight per iteration
    #pragma unroll
    for (int rr = 0; rr < RT / 4; ++rr) {
        int t = t0 + rr * 4 + sub;            // wave-uniform
        int lo = 0, hi = S_;                  // first i with c[i] > t
        #pragma unroll
        for (int it = 0; it < 9; ++it) {
            int mid = (lo + hi) >> 1;
            if (c[mid] <= t) lo = mid + 1; else hi = mid;
        }
        bool valid = t < mel;
        int idx = lo < (S_ - 1) ? lo : (S_ - 1);
        float4 v = make_float4(0.f, 0.f, 0.f, 0.f);
        if (valid) v = ((const float4*)x)[(((b * S_ + idx) * D_) >> 2) + lane];
        ((float4*)out)[(((size_t)(b * T_ + t) * D_) >> 2) + lane] = v;
    }
    if (tid < RT) {
        int t = t0 + tid;
        out[OUT_MELMASK + b * T_ + t] = mm[b * T_ + t] ? 1.0f : 0.0f;
    }
}

extern "C" void kernel_launch(void* const* d_in, const int* in_sizes, int n_in,
                              void* d_out, int out_size, void* d_ws, size_t ws_size,
                              hipStream_t stream)
{
    const float* x          = (const float*)d_in[0];
    const unsigned char* sm = (const unsigned char*)d_in[1];
    const unsigned char* mm = (const unsigned char*)d_in[2];
    const int*   dt         = (const int*)d_in[3];
    // d_in[4] = max_len (hardcoded T_=4096)
    const float* w1 = (const float*)d_in[5];
    const float* b1 = (const float*)d_in[6];
    const float* g1 = (const float*)d_in[7];
    const float* be1= (const float*)d_in[8];
    const float* w2 = (const float*)d_in[9];
    const float* b2 = (const float*)d_in[10];
    const float* g2 = (const float*)d_in[11];
    const float* be2= (const float*)d_in[12];
    const float* wl = (const float*)d_in[13];
    const float* bl = (const float*)d_in[14];

    float* out = (float*)d_out;
    float* h1  = (float*)d_ws;                                  // B*S*D f32 = 33.5 MB
    int*   cum = (int*)((char*)d_ws + (size_t)B_ * S_ * D_ * 4); // B*S int

    conv_ln_kernel<0><<<B_ * S_ / TS, 256, 0, stream>>>(
        x, w1, b1, g1, be1, nullptr, nullptr, nullptr, h1, nullptr);
    conv_ln_kernel<1><<<B_ * S_ / TS, 256, 0, stream>>>(
        h1, w2, b2, g2, be2, wl, bl, sm, nullptr, out + OUT_LOGDUR);
    scan_kernel<<<B_, S_, 0, stream>>>(dt, cum, out + OUT_MELLEN);
    gather_kernel<<<B_ * (T_ / RT), 256, 0, stream>>>(x, cum, mm, out);
}

// Round 7
// 377.133 us; speedup vs baseline: 1.9329x; 1.9329x over previous
//
#include <hip/hip_runtime.h>

#define B_ 64
#define S_ 512
#define D_ 256
#define T_ 4096
#define NEG 0.01f
#define EPS 1e-5f

typedef __attribute__((ext_vector_type(8))) short s16x8;
typedef __attribute__((ext_vector_type(4))) float f32x4;

// flat d_out layout (all float32): out | log_dur | mel_len | mel_mask
#define OUT_LOGDUR  (B_*T_*D_)
#define OUT_MELLEN  (OUT_LOGDUR + B_*S_)
#define OUT_MELMASK (OUT_MELLEN + B_)

__device__ __forceinline__ unsigned short f2bf(float f) {
    unsigned u = __builtin_bit_cast(unsigned, f);
    u += 0x7FFFu + ((u >> 16) & 1u);          // round-to-nearest-even
    return (unsigned short)(u >> 16);
}

// ---------------------------------------------------------------------------
// repack both conv weights w[kk][ci][n] (fp32) -> bf16 K-step-major:
// wt[((ks*256 + n)*32 + kk2)] with k = ks*32+kk2 = kk*256+ci.
// B-frag loads then read 16 contiguous bytes per lane, 1KB/wave contiguous.
// ---------------------------------------------------------------------------
__global__ __launch_bounds__(256)
void pack_w_kernel(const float* __restrict__ w1, const float* __restrict__ w2,
                   unsigned short* __restrict__ o1, unsigned short* __restrict__ o2)
{
    int e = (blockIdx.x & 767) * 256 + threadIdx.x;     // 0..196607
    const float* w        = (blockIdx.x < 768) ? w1 : w2;
    unsigned short* o     = (blockIdx.x < 768) ? o1 : o2;
    int kk2 = e & 31, n = (e >> 5) & 255, ks = e >> 13;
    int k = ks * 32 + kk2;                               // global K index
    o[e] = f2bf(w[((k >> 8) * 256 + (k & 255)) * 256 + n]);
}

// ---------------------------------------------------------------------------
// conv1d(k=3,'SAME') + bias + leaky + LN via bf16 MFMA. Block = 64 rows x 256 ch,
// 4 waves (wave w owns n = w*64..+63 as 4x 16-wide tiles; 4x4 16x16x32 frags).
// A-tile (x rows s0-1..s0+64, all 256 ci) staged ONCE in LDS, bf16, XOR-swizzled;
// K = kk*256+ci handled as 3 shifted row views. B-frags straight from global wt.
// LAST=1: log_dur = h@wl + bl instead of storing h.
// ---------------------------------------------------------------------------
template<int IN_BF16, int LAST>
__global__ __launch_bounds__(256)
void conv_mfma_kernel(const void* __restrict__ inp,
                      const unsigned short* __restrict__ wt,
                      const float* __restrict__ bias, const float* __restrict__ g,
                      const float* __restrict__ be, const float* __restrict__ wl,
                      const float* __restrict__ bl,
                      const unsigned char* __restrict__ smask,
                      unsigned short* __restrict__ hout,
                      float* __restrict__ logdur)
{
    __shared__ __align__(16) unsigned short xs[66 * 256]; // 33 KB, row=512B swz
    __shared__ float red[64][4][2];
    __shared__ float muinv[64][2];

    const int tid = threadIdx.x;
    const int b  = blockIdx.x >> 3;
    const int s0 = (blockIdx.x & 7) * 64;

    // ---- stage 66 input rows as bf16, swizzle byte ^= (row&7)<<4 ----
    #pragma unroll
    for (int it = 0; it < 9; ++it) {
        int ch = it * 256 + tid;                 // 16B chunk id
        if (ch < 66 * 32) {
            int row = ch >> 5, c16 = ch & 31;
            int s = s0 - 1 + row;
            s16x8 v = {0,0,0,0,0,0,0,0};
            if (s >= 0 && s < S_) {
                if (IN_BF16) {
                    v = ((const s16x8*)inp)[(b * S_ + s) * 32 + c16];
                } else {
                    const float4* p = (const float4*)inp + (((b * S_ + s) * 256 + c16 * 8) >> 2);
                    float4 lo = p[0], hi = p[1];
                    v[0]=(short)f2bf(lo.x); v[1]=(short)f2bf(lo.y);
                    v[2]=(short)f2bf(lo.z); v[3]=(short)f2bf(lo.w);
                    v[4]=(short)f2bf(hi.x); v[5]=(short)f2bf(hi.y);
                    v[6]=(short)f2bf(hi.z); v[7]=(short)f2bf(hi.w);
                }
            }
            int byte = (row * 512 + c16 * 16) ^ ((row & 7) << 4);
            *(s16x8*)((char*)xs + byte) = v;
        }
    }
    __syncthreads();

    const int wave = tid >> 6, lane = tid & 63;
    const int lrow = lane & 15, lgrp = lane >> 4;
    const int nb = wave * 64;

    f32x4 acc[4][4] = {};

    // ---- K loop: no barriers; A from LDS (swizzled), B from global (L2) ----
    for (int kk = 0; kk < 3; ++kk) {
        #pragma unroll
        for (int c8 = 0; c8 < 8; ++c8) {
            const int ks = kk * 8 + c8;
            s16x8 a[4], bb[4];
            #pragma unroll
            for (int mt = 0; mt < 4; ++mt) {
                int row = mt * 16 + lrow + kk;               // shifted view = conv tap
                int byte = (row * 512 + (c8 * 32 + lgrp * 8) * 2) ^ ((row & 7) << 4);
                a[mt] = *(const s16x8*)((const char*)xs + byte);
            }
            #pragma unroll
            for (int nt = 0; nt < 4; ++nt) {
                int n = nb + nt * 16 + lrow;
                bb[nt] = *(const s16x8*)(wt + ((ks * 256 + n) * 32 + lgrp * 8));
            }
            #pragma unroll
            for (int mt = 0; mt < 4; ++mt)
                #pragma unroll
                for (int nt = 0; nt < 4; ++nt)
                    acc[mt][nt] = __builtin_amdgcn_mfma_f32_16x16x32_bf16(
                        a[mt], bb[nt], acc[mt][nt], 0, 0, 0);
        }
    }

    // ---- epilogue: bias + leaky, LN row stats, normalize (+ optional head) --
    float bn[4], gn[4], ben[4], wln[4];
    #pragma unroll
    for (int nt = 0; nt < 4; ++nt) {
        int n = nb + nt * 16 + lrow;
        bn[nt] = bias[n]; gn[nt] = g[n]; ben[nt] = be[n];
        wln[nt] = LAST ? wl[n] : 0.f;
    }
    #pragma unroll
    for (int mt = 0; mt < 4; ++mt) {
        #pragma unroll
        for (int j = 0; j < 4; ++j) {
            float s1 = 0.f, s2 = 0.f;
            #pragma unroll
            for (int nt = 0; nt < 4; ++nt) {
                float v = acc[mt][nt][j] + bn[nt];
                v = v > 0.f ? v : NEG * v;                   // leaky relu
                acc[mt][nt][j] = v;
                s1 += v; s2 += v * v;
            }
            #pragma unroll
            for (int o = 1; o < 16; o <<= 1) { s1 += __shfl_xor(s1, o); s2 += __shfl_xor(s2, o); }
            if (lrow == 0) {
                int row = mt * 16 + lgrp * 4 + j;            // C-row mapping (m89)
                red[row][wave][0] = s1; red[row][wave][1] = s2;
            }
        }
    }
    __syncthreads();
    if (tid < 64) {
        float s1 = red[tid][0][0] + red[tid][1][0] + red[tid][2][0] + red[tid][3][0];
        float s2 = red[tid][0][1] + red[tid][1][1] + red[tid][2][1] + red[tid][3][1];
        float mu = s1 * (1.f / D_);
        float var = s2 * (1.f / D_) - mu * mu;
        muinv[tid][0] = mu;
        muinv[tid][1] = rsqrtf(var + EPS);
    }
    __syncthreads();
    #pragma unroll
    for (int mt = 0; mt < 4; ++mt) {
        #pragma unroll
        for (int j = 0; j < 4; ++j) {
            int row = mt * 16 + lgrp * 4 + j;
            float mu = muinv[row][0], inv = muinv[row][1];
            float p = 0.f;
            #pragma unroll
            for (int nt = 0; nt < 4; ++nt) {
                float h = (acc[mt][nt][j] - mu) * inv * gn[nt] + ben[nt];
                if (!LAST)
                    hout[(b * S_ + s0 + row) * 256 + nb + nt * 16 + lrow] = f2bf(h);
                else
                    p += h * wln[nt];
            }
            if (LAST) {
                #pragma unroll
                for (int o = 1; o < 16; o <<= 1) p += __shfl_xor(p, o);
                if (lrow == 0) red[row][wave][0] = p;        // reuse (post-muinv)
            }
        }
    }
    if (LAST) {
        __syncthreads();
        if (tid < 64) {
            float v = red[tid][0][0] + red[tid][1][0] + red[tid][2][0] + red[tid][3][0] + bl[0];
            int i = b * S_ + s0 + tid;
            if (smask[i]) v = 0.f;
            logdur[i] = v;
        }
    }
}

// ---------------------------------------------------------------------------
// per-batch inclusive cumsum of durations; mel_len out as float
// ---------------------------------------------------------------------------
__global__ __launch_bounds__(512)
void scan_kernel(const int* __restrict__ dt, int* __restrict__ cum,
                 float* __restrict__ mellen)
{
    __shared__ int sc[S_];
    const int b = blockIdx.x, tid = threadIdx.x;
    sc[tid] = dt[b * S_ + tid] + 4;   // round(dt+4.0) exact for int dt
    __syncthreads();
    for (int off = 1; off < S_; off <<= 1) {
        int add = (tid >= off) ? sc[tid - off] : 0;
        __syncthreads();
        sc[tid] += add;
        __syncthreads();
    }
    cum[b * S_ + tid] = sc[tid];
    if (tid == S_ - 1) mellen[b] = (float)sc[tid];
}

// ---------------------------------------------------------------------------
// length-regulator gather + mel_mask passthrough
// ---------------------------------------------------------------------------
#define RT 16
__global__ __launch_bounds__(256)
void gather_kernel(const float* __restrict__ x, const int* __restrict__ cum,
                   const unsigned char* __restrict__ mm, float* __restrict__ out)
{
    __shared__ int c[S_];
    const int blk = blockIdx.x;
    const int b  = blk / (T_ / RT);
    const int t0 = (blk % (T_ / RT)) * RT;
    const int tid = threadIdx.x;
    c[tid]       = cum[b * S_ + tid];
    c[tid + 256] = cum[b * S_ + tid + 256];
    __syncthreads();
    const int mel = c[S_ - 1];
    const int lane = tid & 63;
    const int sub  = tid >> 6;
    #pragma unroll
    for (int rr = 0; rr < RT / 4; ++rr) {
        int t = t0 + rr * 4 + sub;            // wave-uniform
        int lo = 0, hi = S_;                  // first i with c[i] > t
        #pragma unroll
        for (int it = 0; it < 10; ++it) {     // ceil(log2(513)) = 10 (9 was a bug)
            int mid = (lo + hi) >> 1;
            if (mid < S_ && c[mid] <= t) lo = mid + 1; else hi = mid;
        }
        bool valid = t < mel;
        int idx = lo < (S_ - 1) ? lo : (S_ - 1);
        float4 v = make_float4(0.f, 0.f, 0.f, 0.f);
        if (valid) v = ((const float4*)x)[(((b * S_ + idx) * D_) >> 2) + lane];
        ((float4*)out)[(((size_t)(b * T_ + t) * D_) >> 2) + lane] = v;
    }
    if (tid < RT) {
        int t = t0 + tid;
        out[OUT_MELMASK + b * T_ + t] = mm[b * T_ + t] ? 1.0f : 0.0f;
    }
}

extern "C" void kernel_launch(void* const* d_in, const int* in_sizes, int n_in,
                              void* d_out, int out_size, void* d_ws, size_t ws_size,
                              hipStream_t stream)
{
    const float* x          = (const float*)d_in[0];
    const unsigned char* sm = (const unsigned char*)d_in[1];
    const unsigned char* mm = (const unsigned char*)d_in[2];
    const int*   dt         = (const int*)d_in[3];
    // d_in[4] = max_len (hardcoded T_=4096)
    const float* w1 = (const float*)d_in[5];
    const float* b1 = (const float*)d_in[6];
    const float* g1 = (const float*)d_in[7];
    const float* be1= (const float*)d_in[8];
    const float* w2 = (const float*)d_in[9];
    const float* b2 = (const float*)d_in[10];
    const float* g2 = (const float*)d_in[11];
    const float* be2= (const float*)d_in[12];
    const float* wl = (const float*)d_in[13];
    const float* bl = (const float*)d_in[14];

    float* out = (float*)d_out;
    unsigned short* wt1 = (unsigned short*)d_ws;            // 384 KB
    unsigned short* wt2 = wt1 + 3 * D_ * D_;                // 384 KB
    unsigned short* h1  = wt2 + 3 * D_ * D_;                // B*S*D bf16 = 16.8 MB
    int* cum = (int*)(h1 + (size_t)B_ * S_ * D_);           // B*S int

    pack_w_kernel<<<1536, 256, 0, stream>>>(w1, w2, wt1, wt2);
    conv_mfma_kernel<0,0><<<B_ * S_ / 64, 256, 0, stream>>>(
        x, wt1, b1, g1, be1, nullptr, nullptr, nullptr, h1, nullptr);
    conv_mfma_kernel<1,1><<<B_ * S_ / 64, 256, 0, stream>>>(
        h1, wt2, b2, g2, be2, wl, bl, sm, nullptr, out + OUT_LOGDUR);
    scan_kernel<<<B_, S_, 0, stream>>>(dt, cum, out + OUT_MELLEN);
    gather_kernel<<<B_ * (T_ / RT), 256, 0, stream>>>(x, cum, mm, out);
}